// Round 1
// baseline (3208.669 us; speedup 1.0000x reference)
//
#include <hip/hip_runtime.h>
#include <hip/hip_bf16.h>
#include <math.h>

// GAT 2-layer, fp32. Softmax division deferred to per-node finalize so each
// layer needs exactly one edge pass (atomic accumulate of w and w*h).

__device__ __forceinline__ float leaky02(float e) { return e >= 0.f ? e : 0.2f * e; }
__device__ __forceinline__ float eluf(float v) { return v > 0.f ? v : expm1f(v); }

// ---------------- K1: h1 = x @ W1  (+ a_s1/a_d1 + self-loop init) ----------
// 128x128 tile per block, K chunked 2x64. 256 threads, 8x8 per thread.
__global__ __launch_bounds__(256) void k1_gemm(
    const float* __restrict__ x, const float* __restrict__ W1,
    const float* __restrict__ att_s, const float* __restrict__ att_d,
    float* __restrict__ h1, float* __restrict__ as1, float* __restrict__ ad1,
    float* __restrict__ dn1, float* __restrict__ accum1, int N)
{
    __shared__ float xs[128 * 64];   // [row][k] chunk
    __shared__ float wsh[64 * 128];  // [k][col] chunk
    const int tid = threadIdx.x;
    const int row0 = blockIdx.x * 128;
    const int tx = tid & 15, ty = tid >> 4;
    const int c0 = tx * 8;
    const int ty8 = ty * 8;

    float acc[8][8];
    #pragma unroll
    for (int i = 0; i < 8; ++i)
        #pragma unroll
        for (int j = 0; j < 8; ++j) acc[i][j] = 0.f;

    for (int kc = 0; kc < 2; ++kc) {
        // stage x chunk: 128 rows x 64 k = 8192 floats
        #pragma unroll
        for (int i = 0; i < 8; ++i) {
            int fi = (tid + i * 256) * 4;       // flat float idx in chunk
            int r = fi >> 6;
            int k = fi & 63;
            float4 v = {0.f, 0.f, 0.f, 0.f};
            if (row0 + r < N)
                v = *(const float4*)&x[(size_t)(row0 + r) * 128 + kc * 64 + k];
            *(float4*)&xs[r * 64 + k] = v;
        }
        // stage W chunk: contiguous 8192 floats
        const float* wsrc = W1 + kc * 64 * 128;
        #pragma unroll
        for (int i = 0; i < 8; ++i) {
            int fi = (tid + i * 256) * 4;
            *(float4*)&wsh[fi] = *(const float4*)&wsrc[fi];
        }
        __syncthreads();

        #pragma unroll 2
        for (int k = 0; k < 64; k += 4) {
            float4 xa[8];
            float4 wa[4][2];
            #pragma unroll
            for (int i = 0; i < 8; ++i)
                xa[i] = *(const float4*)&xs[(ty8 + i) * 64 + k];
            #pragma unroll
            for (int kk = 0; kk < 4; ++kk) {
                wa[kk][0] = *(const float4*)&wsh[(k + kk) * 128 + c0];
                wa[kk][1] = *(const float4*)&wsh[(k + kk) * 128 + c0 + 4];
            }
            #pragma unroll
            for (int i = 0; i < 8; ++i) {
                float xv[4] = {xa[i].x, xa[i].y, xa[i].z, xa[i].w};
                #pragma unroll
                for (int kk = 0; kk < 4; ++kk) {
                    acc[i][0] = fmaf(xv[kk], wa[kk][0].x, acc[i][0]);
                    acc[i][1] = fmaf(xv[kk], wa[kk][0].y, acc[i][1]);
                    acc[i][2] = fmaf(xv[kk], wa[kk][0].z, acc[i][2]);
                    acc[i][3] = fmaf(xv[kk], wa[kk][0].w, acc[i][3]);
                    acc[i][4] = fmaf(xv[kk], wa[kk][1].x, acc[i][4]);
                    acc[i][5] = fmaf(xv[kk], wa[kk][1].y, acc[i][5]);
                    acc[i][6] = fmaf(xv[kk], wa[kk][1].z, acc[i][6]);
                    acc[i][7] = fmaf(xv[kk], wa[kk][1].w, acc[i][7]);
                }
            }
        }
        __syncthreads();
    }

    // epilogue: per-head attention dots. This thread's 8 cols all lie in head
    // tx>>2 (cols c0..c0+7, head = c0/32). Quad lanes tx&~3..tx|3 cover the
    // head's 32 cols -> reduce with shfl_xor 1,2.
    const int head = tx >> 2;
    const int cbase = c0 & 31;
    float asv[8], adv[8];
    #pragma unroll
    for (int i = 0; i < 8; ++i) {
        float s = 0.f, d = 0.f;
        #pragma unroll
        for (int j = 0; j < 8; ++j) {
            float av = acc[i][j];
            s = fmaf(av, att_s[head * 32 + cbase + j], s);
            d = fmaf(av, att_d[head * 32 + cbase + j], d);
        }
        asv[i] = s; adv[i] = d;
    }
    #pragma unroll
    for (int i = 0; i < 8; ++i) {
        asv[i] += __shfl_xor(asv[i], 1); asv[i] += __shfl_xor(asv[i], 2);
        adv[i] += __shfl_xor(adv[i], 1); adv[i] += __shfl_xor(adv[i], 2);
    }
    #pragma unroll
    for (int i = 0; i < 8; ++i) {
        int row = row0 + ty8 + i;
        if (row >= N) continue;
        float e = leaky02(asv[i] + adv[i]);
        float w = __expf(e);            // self-loop unnormalized weight
        float4 h0 = {acc[i][0], acc[i][1], acc[i][2], acc[i][3]};
        float4 h1v = {acc[i][4], acc[i][5], acc[i][6], acc[i][7]};
        *(float4*)&h1[(size_t)row * 128 + c0] = h0;
        *(float4*)&h1[(size_t)row * 128 + c0 + 4] = h1v;
        float4 a0 = {w * h0.x, w * h0.y, w * h0.z, w * h0.w};
        float4 a1 = {w * h1v.x, w * h1v.y, w * h1v.z, w * h1v.w};
        *(float4*)&accum1[(size_t)row * 128 + c0] = a0;
        *(float4*)&accum1[(size_t)row * 128 + c0 + 4] = a1;
        if ((tx & 3) == 0) {
            as1[row * 4 + head] = asv[i];
            ad1[row * 4 + head] = adv[i];
            dn1[row * 4 + head] = w;
        }
    }
}

// ---------------- K2: edge pass, layer 1 (32 lanes / edge) ------------------
__global__ __launch_bounds__(256) void k2_edge1(
    const int* __restrict__ ei, const float* __restrict__ as1,
    const float* __restrict__ ad1, const float* __restrict__ h1,
    float* __restrict__ dn1, float* __restrict__ accum1, int E)
{
    int g = blockIdx.x * 256 + threadIdx.x;
    int edge = g >> 5;
    if (edge >= E) return;
    int lane = g & 31;
    int s = ei[edge];
    int d = ei[E + edge];
    int head = lane >> 3;                       // lane*4 cols -> head
    float e = leaky02(as1[s * 4 + head] + ad1[d * 4 + head]);
    float w = __expf(e);
    if ((lane & 7) == 0) atomicAdd(&dn1[d * 4 + head], w);
    float4 hv = *(const float4*)&h1[(size_t)s * 128 + lane * 4];
    float* ap = &accum1[(size_t)d * 128 + lane * 4];
    atomicAdd(ap + 0, w * hv.x);
    atomicAdd(ap + 1, w * hv.y);
    atomicAdd(ap + 2, w * hv.z);
    atomicAdd(ap + 3, w * hv.w);
}

// ---------------- K3: finalize layer1, elu, h2 = x2 @ W2, self-loop init ----
// 128 threads = 128 nodes per block; x2 staged in LDS (c chunked 2x64).
__global__ __launch_bounds__(128) void k3_node2(
    const float* __restrict__ accum1, const float* __restrict__ dn1,
    const float* __restrict__ b1, const float* __restrict__ W2,
    const float* __restrict__ att_s2, const float* __restrict__ att_d2,
    float* __restrict__ h2, float* __restrict__ as2, float* __restrict__ ad2,
    float* __restrict__ dn2, float* __restrict__ out, int N)
{
    __shared__ float x2s[128 * 68];   // [node][c-chunk], +4 pad
    __shared__ float w2t[16 * 128];   // transposed W2: [j][c]
    const int tid = threadIdx.x;
    const int n0 = blockIdx.x * 128;

    // stage W2 transposed (2048 floats)
    #pragma unroll
    for (int i = 0; i < 4; ++i) {
        int fi = (tid + i * 128) * 4;     // covers c = fi>>4, j = fi&15..+3
        int c = fi >> 4, j = fi & 15;
        float4 v = *(const float4*)&W2[fi];
        w2t[(j + 0) * 128 + c] = v.x;
        w2t[(j + 1) * 128 + c] = v.y;
        w2t[(j + 2) * 128 + c] = v.z;
        w2t[(j + 3) * 128 + c] = v.w;
    }

    float acc[16];
    #pragma unroll
    for (int j = 0; j < 16; ++j) acc[j] = 0.f;
    const int n = n0 + tid;

    for (int cc = 0; cc < 2; ++cc) {
        __syncthreads();   // w2t ready (cc=0) / x2s reads of prev chunk done
        #pragma unroll
        for (int i = 0; i < 16; ++i) {
            int fi = (tid + i * 128) * 4;   // 0..8191
            int r = fi >> 6, c = fi & 63;
            int nn = n0 + r;
            if (nn < N) {
                int gc = cc * 64 + c;
                float4 v = *(const float4*)&accum1[(size_t)nn * 128 + gc];
                float inv = 1.0f / dn1[nn * 4 + (gc >> 5)];
                float4 xv;
                xv.x = eluf(fmaf(v.x, inv, b1[gc + 0]));
                xv.y = eluf(fmaf(v.y, inv, b1[gc + 1]));
                xv.z = eluf(fmaf(v.z, inv, b1[gc + 2]));
                xv.w = eluf(fmaf(v.w, inv, b1[gc + 3]));
                *(float4*)&x2s[r * 68 + c] = xv;
            }
        }
        __syncthreads();
        if (n < N) {
            #pragma unroll
            for (int c = 0; c < 64; c += 4) {
                float4 xv = *(const float4*)&x2s[tid * 68 + c];
                #pragma unroll
                for (int j = 0; j < 16; ++j) {
                    float4 wv = *(const float4*)&w2t[j * 128 + cc * 64 + c];
                    float t = fmaf(xv.x, wv.x, fmaf(xv.y, wv.y,
                              fmaf(xv.z, wv.z, xv.w * wv.w)));
                    acc[j] += t;
                }
            }
        }
    }

    if (n < N) {
        float s2 = 0.f, d2 = 0.f;
        #pragma unroll
        for (int j = 0; j < 16; ++j) {
            s2 = fmaf(acc[j], att_s2[j], s2);
            d2 = fmaf(acc[j], att_d2[j], d2);
        }
        as2[n] = s2; ad2[n] = d2;
        float w = __expf(leaky02(s2 + d2));
        dn2[n] = w;
        #pragma unroll
        for (int q = 0; q < 4; ++q) {
            float4 hv = {acc[q*4+0], acc[q*4+1], acc[q*4+2], acc[q*4+3]};
            *(float4*)&h2[(size_t)n * 16 + q * 4] = hv;
            float4 ov = {w * hv.x, w * hv.y, w * hv.z, w * hv.w};
            *(float4*)&out[(size_t)n * 16 + q * 4] = ov;
        }
    }
}

// ---------------- K4: edge pass, layer 2 (16 lanes / edge) ------------------
__global__ __launch_bounds__(256) void k4_edge2(
    const int* __restrict__ ei, const float* __restrict__ as2,
    const float* __restrict__ ad2, const float* __restrict__ h2,
    float* __restrict__ dn2, float* __restrict__ out, int E)
{
    int g = blockIdx.x * 256 + threadIdx.x;
    int edge = g >> 4;
    if (edge >= E) return;
    int j = g & 15;
    int s = ei[edge];
    int d = ei[E + edge];
    float w = __expf(leaky02(as2[s] + ad2[d]));
    if (j == 0) atomicAdd(&dn2[d], w);
    atomicAdd(&out[(size_t)d * 16 + j], w * h2[(size_t)s * 16 + j]);
}

// ---------------- K5: normalize + bias --------------------------------------
__global__ __launch_bounds__(256) void k5_final(
    float* __restrict__ out, const float* __restrict__ dn2,
    const float* __restrict__ b2, int N)
{
    int t = blockIdx.x * 256 + threadIdx.x;
    if (t >= N * 16) return;
    out[t] = out[t] / dn2[t >> 4] + b2[t & 15];
}

extern "C" void kernel_launch(void* const* d_in, const int* in_sizes, int n_in,
                              void* d_out, int out_size, void* d_ws, size_t ws_size,
                              hipStream_t stream) {
    const float* x    = (const float*)d_in[0];
    const int*   ei   = (const int*)d_in[1];
    const float* W1   = (const float*)d_in[2];
    const float* ats1 = (const float*)d_in[3];
    const float* atd1 = (const float*)d_in[4];
    const float* b1   = (const float*)d_in[5];
    const float* W2   = (const float*)d_in[6];
    const float* ats2 = (const float*)d_in[7];
    const float* atd2 = (const float*)d_in[8];
    const float* b2   = (const float*)d_in[9];
    float* out = (float*)d_out;
    const int N = in_sizes[0] / 128;
    const int E = in_sizes[1] / 2;

    float* ws     = (float*)d_ws;        // total N*287 floats ≈ 114.8 MB
    float* h1     = ws;
    float* accum1 = h1 + (size_t)N * 128;
    float* as1    = accum1 + (size_t)N * 128;
    float* ad1    = as1 + (size_t)N * 4;
    float* dn1    = ad1 + (size_t)N * 4;
    float* h2     = dn1 + (size_t)N * 4;
    float* as2    = h2 + (size_t)N * 16;
    float* ad2    = as2 + N;
    float* dn2    = ad2 + N;

    hipLaunchKernelGGL(k1_gemm, dim3((N + 127) / 128), dim3(256), 0, stream,
                       x, W1, ats1, atd1, h1, as1, ad1, dn1, accum1, N);
    hipLaunchKernelGGL(k2_edge1, dim3((E * 32 + 255) / 256), dim3(256), 0, stream,
                       ei, as1, ad1, h1, dn1, accum1, E);
    hipLaunchKernelGGL(k3_node2, dim3((N + 127) / 128), dim3(128), 0, stream,
                       accum1, dn1, b1, W2, ats2, atd2, h2, as2, ad2, dn2, out, N);
    hipLaunchKernelGGL(k4_edge2, dim3((E * 16 + 255) / 256), dim3(256), 0, stream,
                       ei, as2, ad2, h2, dn2, out, E);
    hipLaunchKernelGGL(k5_final, dim3((N * 16 + 255) / 256), dim3(256), 0, stream,
                       out, dn2, b2, N);
}

// Round 2
// 636.948 us; speedup vs baseline: 5.0376x; 5.0376x over previous
//
#include <hip/hip_runtime.h>
#include <hip/hip_bf16.h>
#include <math.h>

// GAT 2-layer, fp32. Round 2: CSR-gather formulation — zero fp32 atomics.
// Per call: k1 (x@W1 + att dots) -> CSR build (hist/scan/scatter, int atomics
// only) -> kg1 (gather layer1 + elu + fused 128x16 GEMM + att dots) ->
// kg2 (gather layer2 -> out). Softmax division deferred to per-node finalize.

__device__ __forceinline__ float leaky02(float e) { return e >= 0.f ? e : 0.2f * e; }
__device__ __forceinline__ float eluf(float v) { return v > 0.f ? v : expm1f(v); }

// ---------------- K1: h1 = x @ W1  (+ a_s1/a_d1) ---------------------------
// 128x128 tile per block, K chunked 2x64. 256 threads, 8x8 per thread.
__global__ __launch_bounds__(256) void k1_gemm(
    const float* __restrict__ x, const float* __restrict__ W1,
    const float* __restrict__ att_s, const float* __restrict__ att_d,
    float* __restrict__ h1, float* __restrict__ as1, float* __restrict__ ad1,
    int N)
{
    __shared__ float xs[128 * 64];   // [row][k] chunk
    __shared__ float wsh[64 * 128];  // [k][col] chunk
    const int tid = threadIdx.x;
    const int row0 = blockIdx.x * 128;
    const int tx = tid & 15, ty = tid >> 4;
    const int c0 = tx * 8;
    const int ty8 = ty * 8;

    float acc[8][8];
    #pragma unroll
    for (int i = 0; i < 8; ++i)
        #pragma unroll
        for (int j = 0; j < 8; ++j) acc[i][j] = 0.f;

    for (int kc = 0; kc < 2; ++kc) {
        #pragma unroll
        for (int i = 0; i < 8; ++i) {
            int fi = (tid + i * 256) * 4;
            int r = fi >> 6;
            int k = fi & 63;
            float4 v = {0.f, 0.f, 0.f, 0.f};
            if (row0 + r < N)
                v = *(const float4*)&x[(size_t)(row0 + r) * 128 + kc * 64 + k];
            *(float4*)&xs[r * 64 + k] = v;
        }
        const float* wsrc = W1 + kc * 64 * 128;
        #pragma unroll
        for (int i = 0; i < 8; ++i) {
            int fi = (tid + i * 256) * 4;
            *(float4*)&wsh[fi] = *(const float4*)&wsrc[fi];
        }
        __syncthreads();

        #pragma unroll 2
        for (int k = 0; k < 64; k += 4) {
            float4 xa[8];
            float4 wa[4][2];
            #pragma unroll
            for (int i = 0; i < 8; ++i)
                xa[i] = *(const float4*)&xs[(ty8 + i) * 64 + k];
            #pragma unroll
            for (int kk = 0; kk < 4; ++kk) {
                wa[kk][0] = *(const float4*)&wsh[(k + kk) * 128 + c0];
                wa[kk][1] = *(const float4*)&wsh[(k + kk) * 128 + c0 + 4];
            }
            #pragma unroll
            for (int i = 0; i < 8; ++i) {
                float xv[4] = {xa[i].x, xa[i].y, xa[i].z, xa[i].w};
                #pragma unroll
                for (int kk = 0; kk < 4; ++kk) {
                    acc[i][0] = fmaf(xv[kk], wa[kk][0].x, acc[i][0]);
                    acc[i][1] = fmaf(xv[kk], wa[kk][0].y, acc[i][1]);
                    acc[i][2] = fmaf(xv[kk], wa[kk][0].z, acc[i][2]);
                    acc[i][3] = fmaf(xv[kk], wa[kk][0].w, acc[i][3]);
                    acc[i][4] = fmaf(xv[kk], wa[kk][1].x, acc[i][4]);
                    acc[i][5] = fmaf(xv[kk], wa[kk][1].y, acc[i][5]);
                    acc[i][6] = fmaf(xv[kk], wa[kk][1].z, acc[i][6]);
                    acc[i][7] = fmaf(xv[kk], wa[kk][1].w, acc[i][7]);
                }
            }
        }
        __syncthreads();
    }

    const int head = tx >> 2;
    const int cbase = c0 & 31;
    float asv[8], adv[8];
    #pragma unroll
    for (int i = 0; i < 8; ++i) {
        float s = 0.f, d = 0.f;
        #pragma unroll
        for (int j = 0; j < 8; ++j) {
            float av = acc[i][j];
            s = fmaf(av, att_s[head * 32 + cbase + j], s);
            d = fmaf(av, att_d[head * 32 + cbase + j], d);
        }
        asv[i] = s; adv[i] = d;
    }
    #pragma unroll
    for (int i = 0; i < 8; ++i) {
        asv[i] += __shfl_xor(asv[i], 1); asv[i] += __shfl_xor(asv[i], 2);
        adv[i] += __shfl_xor(adv[i], 1); adv[i] += __shfl_xor(adv[i], 2);
    }
    #pragma unroll
    for (int i = 0; i < 8; ++i) {
        int row = row0 + ty8 + i;
        if (row >= N) continue;
        float4 h0 = {acc[i][0], acc[i][1], acc[i][2], acc[i][3]};
        float4 h1v = {acc[i][4], acc[i][5], acc[i][6], acc[i][7]};
        *(float4*)&h1[(size_t)row * 128 + c0] = h0;
        *(float4*)&h1[(size_t)row * 128 + c0 + 4] = h1v;
        if ((tx & 3) == 0) {
            as1[row * 4 + head] = asv[i];
            ad1[row * 4 + head] = adv[i];
        }
    }
}

// ---------------- CSR build ------------------------------------------------
__global__ __launch_bounds__(256) void khist(
    const int* __restrict__ ei, int* __restrict__ deg, int E)
{
    int e = blockIdx.x * 256 + threadIdx.x;
    if (e < E) atomicAdd(&deg[ei[E + e]], 1);
}

// scan1: block b scans deg[b*1024 .. b*1024+1023] -> local-exclusive into
// rowptr, block total into bsum[b].
__global__ __launch_bounds__(256) void kscan1(
    const int* __restrict__ deg, int* __restrict__ rowptr,
    int* __restrict__ bsum, int N)
{
    __shared__ int lds[256];
    const int t = threadIdx.x;
    const int base = blockIdx.x * 1024 + t * 4;
    int v[4];
    int s = 0;
    #pragma unroll
    for (int j = 0; j < 4; ++j) {
        v[j] = (base + j < N) ? deg[base + j] : 0;
        s += v[j];
    }
    lds[t] = s;
    __syncthreads();
    for (int off = 1; off < 256; off <<= 1) {
        int y = (t >= off) ? lds[t - off] : 0;
        __syncthreads();
        lds[t] += y;
        __syncthreads();
    }
    int run = lds[t] - s;   // exclusive base for this thread
    #pragma unroll
    for (int j = 0; j < 4; ++j) {
        if (base + j < N) rowptr[base + j] = run;
        run += v[j];
    }
    if (t == 255) bsum[blockIdx.x] = lds[255];
}

__global__ __launch_bounds__(128) void kscan2(int* __restrict__ bsum, int NB)
{
    __shared__ int lds[128];
    const int t = threadIdx.x;
    int v = (t < NB) ? bsum[t] : 0;
    lds[t] = v;
    __syncthreads();
    for (int off = 1; off < 128; off <<= 1) {
        int y = (t >= off) ? lds[t - off] : 0;
        __syncthreads();
        lds[t] += y;
        __syncthreads();
    }
    if (t < NB) bsum[t] = lds[t] - v;   // exclusive
}

__global__ __launch_bounds__(256) void kscan3(
    int* __restrict__ rowptr, const int* __restrict__ bsum, int N, int E)
{
    const int base = blockIdx.x * 1024 + threadIdx.x * 4;
    const int add = bsum[blockIdx.x];
    #pragma unroll
    for (int j = 0; j < 4; ++j)
        if (base + j < N) rowptr[base + j] += add;
    if (blockIdx.x == 0 && threadIdx.x == 0) rowptr[N] = E;
}

__global__ __launch_bounds__(256) void kscatter(
    const int* __restrict__ ei, const int* __restrict__ rowptr,
    int* __restrict__ cur, int* __restrict__ colidx, int E)
{
    int e = blockIdx.x * 256 + threadIdx.x;
    if (e >= E) return;
    int s = ei[e];
    int d = ei[E + e];
    int pos = rowptr[d] + atomicAdd(&cur[d], 1);
    colidx[pos] = s;
}

// ---------------- KG1: layer-1 gather + elu + fused x2@W2 ------------------
// One wave per node. lane -> channels (2*lane, 2*lane+1), head = lane/16.
__global__ __launch_bounds__(256) void kg1(
    const int* __restrict__ rowptr, const int* __restrict__ colidx,
    const float* __restrict__ h1, const float* __restrict__ as1,
    const float* __restrict__ ad1, const float* __restrict__ b1,
    const float* __restrict__ W2, const float* __restrict__ ats2,
    const float* __restrict__ atd2,
    float* __restrict__ h2, float* __restrict__ as2, float* __restrict__ ad2,
    int N)
{
    const int d = blockIdx.x * 4 + (threadIdx.x >> 6);
    if (d >= N) return;
    const int lane = threadIdx.x & 63;
    const int c = lane * 2;
    const int head = lane >> 4;

    const float ad_d = ad1[d * 4 + head];
    const float as_d = as1[d * 4 + head];
    const float2 h1d = *(const float2*)&h1[(size_t)d * 128 + c];
    const float wself = __expf(leaky02(as_d + ad_d));
    float accx = wself * h1d.x, accy = wself * h1d.y, den = wself;

    const int i1 = rowptr[d + 1];
    for (int i = rowptr[d]; i < i1; ++i) {
        int s = colidx[i];
        float w = __expf(leaky02(as1[s * 4 + head] + ad_d));
        float2 hv = *(const float2*)&h1[(size_t)s * 128 + c];
        accx = fmaf(w, hv.x, accx);
        accy = fmaf(w, hv.y, accy);
        den += w;
    }

    const float inv = 1.f / den;
    const float x2a = eluf(fmaf(accx, inv, b1[c]));
    const float x2b = eluf(fmaf(accy, inv, b1[c + 1]));

    // partial h2[j] = x2a*W2[c][j] + x2b*W2[c+1][j]
    float p[16];
    const float4* w2a = (const float4*)&W2[c * 16];
    const float4* w2b = (const float4*)&W2[(c + 1) * 16];
    #pragma unroll
    for (int q = 0; q < 4; ++q) {
        float4 wa = w2a[q], wb = w2b[q];
        p[q * 4 + 0] = fmaf(x2a, wa.x, x2b * wb.x);
        p[q * 4 + 1] = fmaf(x2a, wa.y, x2b * wb.y);
        p[q * 4 + 2] = fmaf(x2a, wa.z, x2b * wb.z);
        p[q * 4 + 3] = fmaf(x2a, wa.w, x2b * wb.w);
    }
    // butterfly-reduce 16 values across the wave
    #pragma unroll
    for (int m = 1; m < 64; m <<= 1) {
        #pragma unroll
        for (int j = 0; j < 16; ++j) p[j] += __shfl_xor(p[j], m);
    }
    // all lanes now hold the full h2 row
    float s2 = 0.f, d2 = 0.f;
    #pragma unroll
    for (int j = 0; j < 16; ++j) {
        s2 = fmaf(p[j], ats2[j], s2);
        d2 = fmaf(p[j], atd2[j], d2);
    }
    if (lane == 0) { as2[d] = s2; ad2[d] = d2; }
    if (lane < 4) {
        float4 hv = {p[lane * 4 + 0], p[lane * 4 + 1],
                     p[lane * 4 + 2], p[lane * 4 + 3]};
        *(float4*)&h2[(size_t)d * 16 + lane * 4] = hv;
    }
}

// ---------------- KG2: layer-2 gather -> out -------------------------------
// One wave per node: 4 edge-parallel groups x 16 channels.
__global__ __launch_bounds__(256) void kg2(
    const int* __restrict__ rowptr, const int* __restrict__ colidx,
    const float* __restrict__ h2, const float* __restrict__ as2,
    const float* __restrict__ ad2, const float* __restrict__ b2,
    float* __restrict__ out, int N)
{
    const int d = blockIdx.x * 4 + (threadIdx.x >> 6);
    if (d >= N) return;
    const int lane = threadIdx.x & 63;
    const int j = lane & 15, g = lane >> 4;

    const float ad_d = ad2[d];
    float acc = 0.f, den = 0.f;
    const int i1 = rowptr[d + 1];
    for (int i = rowptr[d] + g; i < i1; i += 4) {
        int s = colidx[i];
        float w = __expf(leaky02(as2[s] + ad_d));
        acc = fmaf(w, h2[(size_t)s * 16 + j], acc);
        den += w;
    }
    acc += __shfl_xor(acc, 16); acc += __shfl_xor(acc, 32);
    den += __shfl_xor(den, 16); den += __shfl_xor(den, 32);

    const float wself = __expf(leaky02(as2[d] + ad_d));
    acc = fmaf(wself, h2[(size_t)d * 16 + j], acc);
    den += wself;
    if (g == 0) out[(size_t)d * 16 + j] = acc / den + b2[j];
}

extern "C" void kernel_launch(void* const* d_in, const int* in_sizes, int n_in,
                              void* d_out, int out_size, void* d_ws, size_t ws_size,
                              hipStream_t stream) {
    const float* x    = (const float*)d_in[0];
    const int*   ei   = (const int*)d_in[1];
    const float* W1   = (const float*)d_in[2];
    const float* ats1 = (const float*)d_in[3];
    const float* atd1 = (const float*)d_in[4];
    const float* b1   = (const float*)d_in[5];
    const float* W2   = (const float*)d_in[6];
    const float* ats2 = (const float*)d_in[7];
    const float* atd2 = (const float*)d_in[8];
    const float* b2   = (const float*)d_in[9];
    float* out = (float*)d_out;
    const int N = in_sizes[0] / 128;
    const int E = in_sizes[1] / 2;

    float* ws  = (float*)d_ws;
    float* h1  = ws;                               // 128N
    float* as1 = h1 + (size_t)N * 128;             // 4N
    float* ad1 = as1 + (size_t)N * 4;              // 4N
    float* h2  = ad1 + (size_t)N * 4;              // 16N
    float* as2 = h2 + (size_t)N * 16;              // N
    float* ad2 = as2 + N;                          // N
    int* deg    = (int*)(ad2 + N);                 // N
    int* cur    = deg + N;                         // N
    int* rowptr = cur + N;                         // N+1
    int* bsum   = rowptr + N + 1;                  // 128
    int* colidx = bsum + 128;                      // E

    const int NB = (N + 1023) / 1024;              // scan blocks (98)

    hipMemsetAsync(deg, 0, (size_t)N * sizeof(int), stream);
    hipMemsetAsync(cur, 0, (size_t)N * sizeof(int), stream);

    hipLaunchKernelGGL(k1_gemm, dim3((N + 127) / 128), dim3(256), 0, stream,
                       x, W1, ats1, atd1, h1, as1, ad1, N);
    hipLaunchKernelGGL(khist, dim3((E + 255) / 256), dim3(256), 0, stream,
                       ei, deg, E);
    hipLaunchKernelGGL(kscan1, dim3(NB), dim3(256), 0, stream,
                       deg, rowptr, bsum, N);
    hipLaunchKernelGGL(kscan2, dim3(1), dim3(128), 0, stream, bsum, NB);
    hipLaunchKernelGGL(kscan3, dim3(NB), dim3(256), 0, stream,
                       rowptr, bsum, N, E);
    hipLaunchKernelGGL(kscatter, dim3((E + 255) / 256), dim3(256), 0, stream,
                       ei, rowptr, cur, colidx, E);
    hipLaunchKernelGGL(kg1, dim3((N + 3) / 4), dim3(256), 0, stream,
                       rowptr, colidx, h1, as1, ad1, b1, W2, ats2, atd2,
                       h2, as2, ad2, N);
    hipLaunchKernelGGL(kg2, dim3((N + 3) / 4), dim3(256), 0, stream,
                       rowptr, colidx, h2, as2, ad2, b2, out, N);
}

// Round 3
// 504.074 us; speedup vs baseline: 6.3655x; 1.2636x over previous
//
#include <hip/hip_runtime.h>
#include <hip/hip_bf16.h>
#include <math.h>

// GAT 2-layer, fp32. Round 3: CSR gather with 4x software-pipelined edge
// loops (MLP), scalarized colidx loads, rank-based scatter (single atomic
// pass). Softmax division deferred to per-node finalize.

__device__ __forceinline__ float leaky02(float e) { return e >= 0.f ? e : 0.2f * e; }
__device__ __forceinline__ float eluf(float v) { return v > 0.f ? v : expm1f(v); }

// ---------------- K1: h1 = x @ W1  (+ a_s1/a_d1) ---------------------------
__global__ __launch_bounds__(256) void k1_gemm(
    const float* __restrict__ x, const float* __restrict__ W1,
    const float* __restrict__ att_s, const float* __restrict__ att_d,
    float* __restrict__ h1, float* __restrict__ as1, float* __restrict__ ad1,
    int N)
{
    __shared__ float xs[128 * 64];   // [row][k] chunk
    __shared__ float wsh[64 * 128];  // [k][col] chunk
    const int tid = threadIdx.x;
    const int row0 = blockIdx.x * 128;
    const int tx = tid & 15, ty = tid >> 4;
    const int c0 = tx * 8;
    const int ty8 = ty * 8;

    float acc[8][8];
    #pragma unroll
    for (int i = 0; i < 8; ++i)
        #pragma unroll
        for (int j = 0; j < 8; ++j) acc[i][j] = 0.f;

    for (int kc = 0; kc < 2; ++kc) {
        #pragma unroll
        for (int i = 0; i < 8; ++i) {
            int fi = (tid + i * 256) * 4;
            int r = fi >> 6;
            int k = fi & 63;
            float4 v = {0.f, 0.f, 0.f, 0.f};
            if (row0 + r < N)
                v = *(const float4*)&x[(size_t)(row0 + r) * 128 + kc * 64 + k];
            *(float4*)&xs[r * 64 + k] = v;
        }
        const float* wsrc = W1 + kc * 64 * 128;
        #pragma unroll
        for (int i = 0; i < 8; ++i) {
            int fi = (tid + i * 256) * 4;
            *(float4*)&wsh[fi] = *(const float4*)&wsrc[fi];
        }
        __syncthreads();

        #pragma unroll 2
        for (int k = 0; k < 64; k += 4) {
            float4 xa[8];
            float4 wa[4][2];
            #pragma unroll
            for (int i = 0; i < 8; ++i)
                xa[i] = *(const float4*)&xs[(ty8 + i) * 64 + k];
            #pragma unroll
            for (int kk = 0; kk < 4; ++kk) {
                wa[kk][0] = *(const float4*)&wsh[(k + kk) * 128 + c0];
                wa[kk][1] = *(const float4*)&wsh[(k + kk) * 128 + c0 + 4];
            }
            #pragma unroll
            for (int i = 0; i < 8; ++i) {
                float xv[4] = {xa[i].x, xa[i].y, xa[i].z, xa[i].w};
                #pragma unroll
                for (int kk = 0; kk < 4; ++kk) {
                    acc[i][0] = fmaf(xv[kk], wa[kk][0].x, acc[i][0]);
                    acc[i][1] = fmaf(xv[kk], wa[kk][0].y, acc[i][1]);
                    acc[i][2] = fmaf(xv[kk], wa[kk][0].z, acc[i][2]);
                    acc[i][3] = fmaf(xv[kk], wa[kk][0].w, acc[i][3]);
                    acc[i][4] = fmaf(xv[kk], wa[kk][1].x, acc[i][4]);
                    acc[i][5] = fmaf(xv[kk], wa[kk][1].y, acc[i][5]);
                    acc[i][6] = fmaf(xv[kk], wa[kk][1].z, acc[i][6]);
                    acc[i][7] = fmaf(xv[kk], wa[kk][1].w, acc[i][7]);
                }
            }
        }
        __syncthreads();
    }

    const int head = tx >> 2;
    const int cbase = c0 & 31;
    float asv[8], adv[8];
    #pragma unroll
    for (int i = 0; i < 8; ++i) {
        float s = 0.f, d = 0.f;
        #pragma unroll
        for (int j = 0; j < 8; ++j) {
            float av = acc[i][j];
            s = fmaf(av, att_s[head * 32 + cbase + j], s);
            d = fmaf(av, att_d[head * 32 + cbase + j], d);
        }
        asv[i] = s; adv[i] = d;
    }
    #pragma unroll
    for (int i = 0; i < 8; ++i) {
        asv[i] += __shfl_xor(asv[i], 1); asv[i] += __shfl_xor(asv[i], 2);
        adv[i] += __shfl_xor(adv[i], 1); adv[i] += __shfl_xor(adv[i], 2);
    }
    #pragma unroll
    for (int i = 0; i < 8; ++i) {
        int row = row0 + ty8 + i;
        if (row >= N) continue;
        float4 h0 = {acc[i][0], acc[i][1], acc[i][2], acc[i][3]};
        float4 h1v = {acc[i][4], acc[i][5], acc[i][6], acc[i][7]};
        *(float4*)&h1[(size_t)row * 128 + c0] = h0;
        *(float4*)&h1[(size_t)row * 128 + c0 + 4] = h1v;
        if ((tx & 3) == 0) {
            as1[row * 4 + head] = asv[i];
            ad1[row * 4 + head] = adv[i];
        }
    }
}

// ---------------- CSR build ------------------------------------------------
// histogram + per-edge rank within its dst row (single atomic pass)
__global__ __launch_bounds__(256) void khist(
    const int* __restrict__ ei, int* __restrict__ deg,
    int* __restrict__ rank, int E)
{
    int e = blockIdx.x * 256 + threadIdx.x;
    if (e < E) rank[e] = atomicAdd(&deg[ei[E + e]], 1);
}

__global__ __launch_bounds__(256) void kscan1(
    const int* __restrict__ deg, int* __restrict__ rowptr,
    int* __restrict__ bsum, int N)
{
    __shared__ int lds[256];
    const int t = threadIdx.x;
    const int base = blockIdx.x * 1024 + t * 4;
    int v[4];
    int s = 0;
    #pragma unroll
    for (int j = 0; j < 4; ++j) {
        v[j] = (base + j < N) ? deg[base + j] : 0;
        s += v[j];
    }
    lds[t] = s;
    __syncthreads();
    for (int off = 1; off < 256; off <<= 1) {
        int y = (t >= off) ? lds[t - off] : 0;
        __syncthreads();
        lds[t] += y;
        __syncthreads();
    }
    int run = lds[t] - s;
    #pragma unroll
    for (int j = 0; j < 4; ++j) {
        if (base + j < N) rowptr[base + j] = run;
        run += v[j];
    }
    if (t == 255) bsum[blockIdx.x] = lds[255];
}

__global__ __launch_bounds__(128) void kscan2(int* __restrict__ bsum, int NB)
{
    __shared__ int lds[128];
    const int t = threadIdx.x;
    int v = (t < NB) ? bsum[t] : 0;
    lds[t] = v;
    __syncthreads();
    for (int off = 1; off < 128; off <<= 1) {
        int y = (t >= off) ? lds[t - off] : 0;
        __syncthreads();
        lds[t] += y;
        __syncthreads();
    }
    if (t < NB) bsum[t] = lds[t] - v;
}

__global__ __launch_bounds__(256) void kscan3(
    int* __restrict__ rowptr, const int* __restrict__ bsum, int N, int E)
{
    const int base = blockIdx.x * 1024 + threadIdx.x * 4;
    const int add = bsum[blockIdx.x];
    #pragma unroll
    for (int j = 0; j < 4; ++j)
        if (base + j < N) rowptr[base + j] += add;
    if (blockIdx.x == 0 && threadIdx.x == 0) rowptr[N] = E;
}

__global__ __launch_bounds__(256) void kscatter(
    const int* __restrict__ ei, const int* __restrict__ rowptr,
    const int* __restrict__ rank, int* __restrict__ colidx, int E)
{
    int e = blockIdx.x * 256 + threadIdx.x;
    if (e >= E) return;
    colidx[rowptr[ei[E + e]] + rank[e]] = ei[e];
}

// ---------------- KG1: layer-1 gather + elu + fused x2@W2 ------------------
// One wave per node. lane -> channels (2*lane, 2*lane+1), head = lane/16.
// Edge loop batched x4: 4 independent gathers in flight per wave.
__global__ __launch_bounds__(256) void kg1(
    const int* __restrict__ rowptr, const int* __restrict__ colidx,
    const float* __restrict__ h1, const float* __restrict__ as1,
    const float* __restrict__ ad1, const float* __restrict__ b1,
    const float* __restrict__ W2, const float* __restrict__ ats2,
    const float* __restrict__ atd2,
    float* __restrict__ h2, float* __restrict__ as2, float* __restrict__ ad2,
    int N)
{
    const int d = blockIdx.x * 4 + (threadIdx.x >> 6);
    if (d >= N) return;
    const int lane = threadIdx.x & 63;
    const int c = lane * 2;
    const int head = lane >> 4;

    const float ad_d = ad1[d * 4 + head];
    const float as_d = as1[d * 4 + head];
    const float2 h1d = *(const float2*)&h1[(size_t)d * 128 + c];
    const float wself = __expf(leaky02(as_d + ad_d));
    float accx = wself * h1d.x, accy = wself * h1d.y, den = wself;

    int i0 = __builtin_amdgcn_readfirstlane(rowptr[d]);
    int i1 = __builtin_amdgcn_readfirstlane(rowptr[d + 1]);
    int i = i0;
    for (; i + 4 <= i1; i += 4) {
        int s0 = colidx[i + 0];
        int s1 = colidx[i + 1];
        int s2 = colidx[i + 2];
        int s3 = colidx[i + 3];
        float a0 = as1[s0 * 4 + head];
        float a1 = as1[s1 * 4 + head];
        float a2 = as1[s2 * 4 + head];
        float a3 = as1[s3 * 4 + head];
        float2 v0 = *(const float2*)&h1[(size_t)s0 * 128 + c];
        float2 v1 = *(const float2*)&h1[(size_t)s1 * 128 + c];
        float2 v2 = *(const float2*)&h1[(size_t)s2 * 128 + c];
        float2 v3 = *(const float2*)&h1[(size_t)s3 * 128 + c];
        float w0 = __expf(leaky02(a0 + ad_d));
        float w1 = __expf(leaky02(a1 + ad_d));
        float w2 = __expf(leaky02(a2 + ad_d));
        float w3 = __expf(leaky02(a3 + ad_d));
        accx = fmaf(w0, v0.x, accx); accy = fmaf(w0, v0.y, accy);
        accx = fmaf(w1, v1.x, accx); accy = fmaf(w1, v1.y, accy);
        accx = fmaf(w2, v2.x, accx); accy = fmaf(w2, v2.y, accy);
        accx = fmaf(w3, v3.x, accx); accy = fmaf(w3, v3.y, accy);
        den += (w0 + w1) + (w2 + w3);
    }
    for (; i < i1; ++i) {
        int s = colidx[i];
        float w = __expf(leaky02(as1[s * 4 + head] + ad_d));
        float2 hv = *(const float2*)&h1[(size_t)s * 128 + c];
        accx = fmaf(w, hv.x, accx);
        accy = fmaf(w, hv.y, accy);
        den += w;
    }

    const float inv = 1.f / den;
    const float x2a = eluf(fmaf(accx, inv, b1[c]));
    const float x2b = eluf(fmaf(accy, inv, b1[c + 1]));

    // partial h2[j] = x2a*W2[c][j] + x2b*W2[c+1][j]
    float p[16];
    const float4* w2a = (const float4*)&W2[c * 16];
    const float4* w2b = (const float4*)&W2[(c + 1) * 16];
    #pragma unroll
    for (int q = 0; q < 4; ++q) {
        float4 wa = w2a[q], wb = w2b[q];
        p[q * 4 + 0] = fmaf(x2a, wa.x, x2b * wb.x);
        p[q * 4 + 1] = fmaf(x2a, wa.y, x2b * wb.y);
        p[q * 4 + 2] = fmaf(x2a, wa.z, x2b * wb.z);
        p[q * 4 + 3] = fmaf(x2a, wa.w, x2b * wb.w);
    }
    #pragma unroll
    for (int m = 1; m < 64; m <<= 1) {
        #pragma unroll
        for (int j = 0; j < 16; ++j) p[j] += __shfl_xor(p[j], m);
    }
    float s2 = 0.f, d2 = 0.f;
    #pragma unroll
    for (int j = 0; j < 16; ++j) {
        s2 = fmaf(p[j], ats2[j], s2);
        d2 = fmaf(p[j], atd2[j], d2);
    }
    if (lane == 0) { as2[d] = s2; ad2[d] = d2; }
    if (lane < 4) {
        float4 hv = {p[lane * 4 + 0], p[lane * 4 + 1],
                     p[lane * 4 + 2], p[lane * 4 + 3]};
        *(float4*)&h2[(size_t)d * 16 + lane * 4] = hv;
    }
}

// ---------------- KG2: layer-2 gather -> out -------------------------------
// One wave per node: 4 edge-parallel groups x 16 channels, x2 unrolled.
__global__ __launch_bounds__(256) void kg2(
    const int* __restrict__ rowptr, const int* __restrict__ colidx,
    const float* __restrict__ h2, const float* __restrict__ as2,
    const float* __restrict__ ad2, const float* __restrict__ b2,
    float* __restrict__ out, int N)
{
    const int d = blockIdx.x * 4 + (threadIdx.x >> 6);
    if (d >= N) return;
    const int lane = threadIdx.x & 63;
    const int j = lane & 15, g = lane >> 4;

    const float ad_d = ad2[d];
    float acc = 0.f, den = 0.f;
    int i0 = __builtin_amdgcn_readfirstlane(rowptr[d]);
    int i1 = __builtin_amdgcn_readfirstlane(rowptr[d + 1]);
    int i = i0 + g;
    for (; i + 4 < i1; i += 8) {
        int s0 = colidx[i];
        int s1 = colidx[i + 4];
        float a0 = as2[s0];
        float a1 = as2[s1];
        float v0 = h2[(size_t)s0 * 16 + j];
        float v1 = h2[(size_t)s1 * 16 + j];
        float w0 = __expf(leaky02(a0 + ad_d));
        float w1 = __expf(leaky02(a1 + ad_d));
        acc = fmaf(w0, v0, acc);
        acc = fmaf(w1, v1, acc);
        den += w0 + w1;
    }
    for (; i < i1; i += 4) {
        int s = colidx[i];
        float w = __expf(leaky02(as2[s] + ad_d));
        acc = fmaf(w, h2[(size_t)s * 16 + j], acc);
        den += w;
    }
    acc += __shfl_xor(acc, 16); acc += __shfl_xor(acc, 32);
    den += __shfl_xor(den, 16); den += __shfl_xor(den, 32);

    const float wself = __expf(leaky02(as2[d] + ad_d));
    acc = fmaf(wself, h2[(size_t)d * 16 + j], acc);
    den += wself;
    if (g == 0) out[(size_t)d * 16 + j] = acc / den + b2[j];
}

extern "C" void kernel_launch(void* const* d_in, const int* in_sizes, int n_in,
                              void* d_out, int out_size, void* d_ws, size_t ws_size,
                              hipStream_t stream) {
    const float* x    = (const float*)d_in[0];
    const int*   ei   = (const int*)d_in[1];
    const float* W1   = (const float*)d_in[2];
    const float* ats1 = (const float*)d_in[3];
    const float* atd1 = (const float*)d_in[4];
    const float* b1   = (const float*)d_in[5];
    const float* W2   = (const float*)d_in[6];
    const float* ats2 = (const float*)d_in[7];
    const float* atd2 = (const float*)d_in[8];
    const float* b2   = (const float*)d_in[9];
    float* out = (float*)d_out;
    const int N = in_sizes[0] / 128;
    const int E = in_sizes[1] / 2;

    float* ws  = (float*)d_ws;
    float* h1  = ws;                               // 128N
    float* as1 = h1 + (size_t)N * 128;             // 4N
    float* ad1 = as1 + (size_t)N * 4;              // 4N
    float* h2  = ad1 + (size_t)N * 4;              // 16N
    float* as2 = h2 + (size_t)N * 16;              // N
    float* ad2 = as2 + N;                          // N
    int* deg    = (int*)(ad2 + N);                 // N
    int* rowptr = deg + N;                         // N+1
    int* bsum   = rowptr + N + 1;                  // 128
    int* colidx = bsum + 128;                      // E
    int* rank   = colidx + E;                      // E

    const int NB = (N + 1023) / 1024;

    hipMemsetAsync(deg, 0, (size_t)N * sizeof(int), stream);

    hipLaunchKernelGGL(k1_gemm, dim3((N + 127) / 128), dim3(256), 0, stream,
                       x, W1, ats1, atd1, h1, as1, ad1, N);
    hipLaunchKernelGGL(khist, dim3((E + 255) / 256), dim3(256), 0, stream,
                       ei, deg, rank, E);
    hipLaunchKernelGGL(kscan1, dim3(NB), dim3(256), 0, stream,
                       deg, rowptr, bsum, N);
    hipLaunchKernelGGL(kscan2, dim3(1), dim3(128), 0, stream, bsum, NB);
    hipLaunchKernelGGL(kscan3, dim3(NB), dim3(256), 0, stream,
                       rowptr, bsum, N, E);
    hipLaunchKernelGGL(kscatter, dim3((E + 255) / 256), dim3(256), 0, stream,
                       ei, rowptr, rank, colidx, E);
    hipLaunchKernelGGL(kg1, dim3((N + 3) / 4), dim3(256), 0, stream,
                       rowptr, colidx, h1, as1, ad1, b1, W2, ats2, atd2,
                       h2, as2, ad2, N);
    hipLaunchKernelGGL(kg2, dim3((N + 3) / 4), dim3(256), 0, stream,
                       rowptr, colidx, h2, as2, ad2, b2, out, N);
}